// Round 5
// baseline (108.641 us; speedup 1.0000x reference)
//
#include <hip/hip_runtime.h>
#include <hip/hip_bf16.h>

typedef __attribute__((ext_vector_type(4))) float f32x4;
typedef __attribute__((ext_vector_type(16))) float f32x16;
typedef __attribute__((ext_vector_type(8))) short bf16x8;
typedef __attribute__((ext_vector_type(4))) unsigned int u32x4;

#define MFMA16(a,b,c) __builtin_amdgcn_mfma_f32_16x16x32_bf16(a,b,c,0,0,0)
#define MFMA32(a,b,c) __builtin_amdgcn_mfma_f32_32x32x16_bf16(a,b,c,0,0,0)
#define LOG2E 1.44269504088896340736f

__device__ __forceinline__ float bf2f(unsigned short u){
  unsigned v = ((unsigned)u) << 16;
  float f; __builtin_memcpy(&f, &v, 4); return f;
}
__device__ __forceinline__ unsigned short f2bf(float f){
  unsigned x; __builtin_memcpy(&x, &f, 4);
  x += 0x7fffu + ((x >> 16) & 1u);   // RNE
  return (unsigned short)(x >> 16);
}
__device__ __forceinline__ void gload_lds16(const void* g, void* l){
  __builtin_amdgcn_global_load_lds((const __attribute__((address_space(1))) void*)g,
                                   (__attribute__((address_space(3))) void*)l, 16, 0, 0);
}
__device__ __forceinline__ f32x16 zero16(){
  f32x16 z;
#pragma unroll
  for (int i = 0; i < 16; ++i) z[i] = 0.f;
  return z;
}
__device__ __forceinline__ unsigned cvtpk(float lo, float hi_){
  unsigned d;
  asm("v_cvt_pk_bf16_f32 %0, %1, %2" : "=v"(d) : "v"(lo), "v"(hi_));
  return d;
}
// pack 16 per-lane P values (key map (r&3)+8*(r>>2)+4*hi) into two PV A-frags
__device__ __forceinline__ void pack_group(const float* p, bf16x8& f0, bf16x8& f1){
  unsigned a0 = cvtpk(p[0], p[1]),  b0 = cvtpk(p[4],  p[5]);
  unsigned a1 = cvtpk(p[2], p[3]),  b1 = cvtpk(p[6],  p[7]);
  unsigned c0 = cvtpk(p[8], p[9]),  d0 = cvtpk(p[12], p[13]);
  unsigned c1 = cvtpk(p[10],p[11]), d1 = cvtpk(p[14], p[15]);
  asm("v_permlane32_swap_b32 %0, %1" : "+v"(a0), "+v"(b0));
  asm("v_permlane32_swap_b32 %0, %1" : "+v"(a1), "+v"(b1));
  asm("v_permlane32_swap_b32 %0, %1" : "+v"(c0), "+v"(d0));
  asm("v_permlane32_swap_b32 %0, %1" : "+v"(c1), "+v"(d1));
  u32x4 w0 = {a0, a1, b0, b1};
  u32x4 w1 = {c0, c1, d0, d1};
  f0 = __builtin_bit_cast(bf16x8, w0);
  f1 = __builtin_bit_cast(bf16x8, w1);
}

// ---------------- cast x (fp32 -> bf16), 4 elems/thread ----------------
__global__ void k_cast(const float* __restrict__ src, unsigned short* __restrict__ dst){
  const int i = blockIdx.x * 256 + threadIdx.x;
  const float4 v = ((const float4*)src)[i];
  ushort4 o;
  o.x = f2bf(v.x); o.y = f2bf(v.y); o.z = f2bf(v.z); o.w = f2bf(v.w);
  ((ushort4*)dst)[i] = o;
}

// ---------------- transpose-cast weights: src [R][C] f32 -> dst [C][R] bf16 ----------------
__global__ void k_castT(const float* __restrict__ src, unsigned short* __restrict__ dst,
                        const int R, const int C){
  __shared__ unsigned short t[64][65];
  const int r0 = blockIdx.y * 64, c0 = blockIdx.x * 64;
  const int tid = threadIdx.x;
#pragma unroll
  for (int i = 0; i < 16; ++i){
    int idx = i*256 + tid; int r = idx >> 6, c = idx & 63;
    t[r][c] = f2bf(src[(size_t)(r0 + r)*C + c0 + c]);
  }
  __syncthreads();
#pragma unroll
  for (int i = 0; i < 16; ++i){
    int idx = i*256 + tid; int c = idx >> 6, r = idx & 63;
    dst[(size_t)(c0 + c)*R + r0 + r] = t[r][c];
  }
}

// ============ QKV GEMM: 256x256 tile, BK=64, 8-phase counted-vmcnt schedule ============
// A = xb[4096][1024], B = waT[3072][1024]. LDS swizzle: 16B chunk index ch' = ch ^ (row&7),
// staged via pre-swizzled global source (linear LDS dest), read with the same XOR.
__global__ __launch_bounds__(512,2) void k_gemm_qkv(const unsigned short* __restrict__ xb,
    const unsigned short* __restrict__ waT, const float* __restrict__ b_attn,
    unsigned short* __restrict__ qb, unsigned short* __restrict__ kb,
    unsigned short* __restrict__ vb)
{
  __shared__ char lds[131072];                 // [2 buf][A 32KB | B 32KB]
  const int K = 1024, NT = 16;
  const int tid = threadIdx.x, lane = tid & 63, wave = tid >> 6;
  const int wr = wave >> 2, wc = wave & 3;
  const int l15 = lane & 15, lg = lane >> 4;

  int wgid = blockIdx.y * 12 + blockIdx.x;     // nwg = 192, %8 == 0
  wgid = (wgid & 7) * 24 + (wgid >> 3);        // XCD swizzle
  const int bm = (wgid / 12) * 256, bn = (wgid % 12) * 256;

  // staging geometry: logical instr i covers rows [i*64, i*64+64) of the 256-row operand
  const int soff = wave*1024 + lane*16;        // byte offset within one 8KB instr slab
  const int srow = soff >> 7;                  // 0..63
  const int schv = ((soff >> 4) & 7) ^ (srow & 7);
  const unsigned short* gA = xb  + (size_t)(bm + srow)*K + schv*8;
  const unsigned short* gB = waT + (size_t)(bn + srow)*K + schv*8;
  const int ldst = wave*1024;
  char* const ldsp = (char*)lds;

  // fragment geometry: row = (...)+l15, chunk ck = ks*4+lg, read at ch' = ck ^ (l15&7)
  const int c0 = ((lg    ) ^ (l15 & 7)) * 16;  // ks=0
  const int c1 = ((4 + lg) ^ (l15 & 7)) * 16;  // ks=1
  const int laneA = l15 * 128;

  f32x4 acc[8][4];
#pragma unroll
  for (int m = 0; m < 8; ++m)
#pragma unroll
    for (int n = 0; n < 4; ++n) acc[m][n] = (f32x4){0.f,0.f,0.f,0.f};

#define STG(T, PR) do { if ((T) < NT) { \
    const int b_ = (T) & 1; const int i0_ = ((PR) & 1) * 2; \
    if ((PR) < 2) { \
      gload_lds16(gA + (size_t)(i0_  )*64*1024 + (T)*64, ldsp + b_*65536 + (i0_  )*8192 + ldst); \
      gload_lds16(gA + (size_t)(i0_+1)*64*1024 + (T)*64, ldsp + b_*65536 + (i0_+1)*8192 + ldst); \
    } else { \
      gload_lds16(gB + (size_t)(i0_  )*64*1024 + (T)*64, ldsp + b_*65536 + 32768 + (i0_  )*8192 + ldst); \
      gload_lds16(gB + (size_t)(i0_+1)*64*1024 + (T)*64, ldsp + b_*65536 + 32768 + (i0_+1)*8192 + ldst); \
    } } } while(0)

#define LDA(MH) _Pragma("unroll") for (int m = 0; m < 4; ++m){ \
    a[2*m]   = *(const bf16x8*)(Aw + (MH)*8192 + m*2048 + c0); \
    a[2*m+1] = *(const bf16x8*)(Aw + (MH)*8192 + m*2048 + c1); }
#define LDB(NH) _Pragma("unroll") for (int n = 0; n < 2; ++n){ \
    b[2*((NH)*2+n)]   = *(const bf16x8*)(Bw + ((NH)*2+n)*2048 + c0); \
    b[2*((NH)*2+n)+1] = *(const bf16x8*)(Bw + ((NH)*2+n)*2048 + c1); }
#define P_MFMA(MH, NLO) \
  __builtin_amdgcn_s_setprio(1); \
  _Pragma("unroll") for (int m = 0; m < 4; ++m){ \
    _Pragma("unroll") for (int n = 0; n < 2; ++n){ \
      acc[(MH)*4+m][(NLO)+n] = MFMA16(a[2*m],   b[2*((NLO)+n)],   acc[(MH)*4+m][(NLO)+n]); \
      acc[(MH)*4+m][(NLO)+n] = MFMA16(a[2*m+1], b[2*((NLO)+n)+1], acc[(MH)*4+m][(NLO)+n]); \
    } } \
  __builtin_amdgcn_s_setprio(0);
#define WAIT_LGKM asm volatile("s_waitcnt lgkmcnt(0)" ::: "memory"); __builtin_amdgcn_sched_barrier(0);

  // prologue: tile0 fully, tile1 pair0
  STG(0,0); STG(0,1); STG(0,2); STG(0,3); STG(1,0);

  bf16x8 a[8], b[8];
  for (int t = 0; t < NT; ++t){
    const char* Aw = ldsp + (t&1)*65536 + wr*16384 + laneA;
    const char* Bw = ldsp + (t&1)*65536 + 32768 + wc*8192 + laneA;
    // tile t fully landed across all waves (only tile t+1 pair0 = 2 instrs younger)
    asm volatile("s_waitcnt vmcnt(2)" ::: "memory");
    __builtin_amdgcn_s_barrier();
    // P1: A[mh0] (8 reads) + B[n0,1] (4 reads); stage t+1 pair1
    LDA(0); LDB(0);
    STG(t+1, 1);
    __builtin_amdgcn_s_barrier();
    WAIT_LGKM;
    P_MFMA(0, 0);
    // P2: B[n2,3]; stage t+1 pair2
    LDB(1);
    STG(t+1, 2);
    __builtin_amdgcn_s_barrier();
    WAIT_LGKM;
    P_MFMA(0, 2);
    // P3: A[mh1]; stage t+1 pair3
    LDA(1);
    STG(t+1, 3);
    __builtin_amdgcn_s_barrier();
    WAIT_LGKM;
    P_MFMA(1, 2);
    __builtin_amdgcn_s_barrier();   // close: all reads of buf (t&1) complete before P4 stages into it
    // P4: stage t+2 pair0; MFMA mh1 x n0,1 (regs only)
    STG(t+2, 0);
    P_MFMA(1, 0);
  }
#undef STG
#undef LDA
#undef LDB
#undef P_MFMA
#undef WAIT_LGKM

  // epilogue: scatter q/k/v (k,v in tiled+swizzled attention layouts)
#pragma unroll
  for (int am = 0; am < 8; ++am){
#pragma unroll
    for (int an = 0; an < 4; ++an){
#pragma unroll
      for (int r = 0; r < 4; ++r){
        const int row = bm + wr*128 + am*16 + lg*4 + r;
        const int col = bn + wc*64 + an*16 + l15;
        const float val = acc[am][an][r] + b_attn[col];
        const int part = col >> 10, c = col & 1023;
        const int h = c >> 6, d = c & 63;
        const int bb = row >> 11, tt = row & 2047;
        const unsigned short u = f2bf(val);
        const size_t bhbase = (size_t)(bb*16 + h)*131072;
        if (part == 0){
          qb[bhbase + (size_t)tt*64 + d] = u;
        } else {
          const int tile = tt >> 6, l = tt & 63;
          const size_t base = bhbase + (size_t)tile*4096;
          if (part == 1) kb[base + l*64 + ((((d>>3)^(l&7))<<3) | (d&7))] = u;   // K[key][d], swz
          else           vb[base + d*64 + ((((l>>3)^(d&7))<<3) | (l&7))] = u;   // V^T[d][key], swz
        }
      }
    }
  }
}

// ---------------- shared GEMM mainloop (128x128) for proj ----------------
__device__ __forceinline__ void gemm_core(const unsigned short* __restrict__ A,
                                          const unsigned short* __restrict__ Bt,
                                          const int K, const int bm, const int bn,
                                          unsigned short* lds, f32x4 acc[4][4])
{
  const int tid  = threadIdx.x;
  const int lane = tid & 63;
  const int wave = tid >> 6;
  const int wr = wave >> 1, wc = wave & 1;
  const int l15 = lane & 15, lg = lane >> 4;
  char* ldsb = (char*)lds;
  const int aoff = (wr*64 + l15)*64 + lg*16;
  const int boff = 8192 + (wc*64 + l15)*64 + lg*16;
  const int o0 = wave*1024 + lane*16;
  const int o1 = o0 + 4096;
  const int r0_ = o0 >> 6, c0_ = (o0 & 63) >> 1;
  const int r1_ = o1 >> 6, c1_ = (o1 & 63) >> 1;
  const unsigned short* Ap0 = A  + (size_t)(bm + r0_)*K + c0_;
  const unsigned short* Ap1 = A  + (size_t)(bm + r1_)*K + c1_;
  const unsigned short* Bp0 = Bt + (size_t)(bn + r0_)*K + c0_;
  const unsigned short* Bp1 = Bt + (size_t)(bn + r1_)*K + c1_;
  char* dA0 = ldsb + wave*1024;
  char* dA1 = ldsb + 4096 + wave*1024;
  char* dB0 = ldsb + 8192 + wave*1024;
  char* dB1 = ldsb + 12288 + wave*1024;
  for (int k0 = 0; k0 < K; k0 += 32){
    __syncthreads();
    gload_lds16(Ap0 + k0, dA0);
    gload_lds16(Ap1 + k0, dA1);
    gload_lds16(Bp0 + k0, dB0);
    gload_lds16(Bp1 + k0, dB1);
    __syncthreads();
    bf16x8 af[4], bg[4];
#pragma unroll
    for (int m = 0; m < 4; ++m) af[m] = *(const bf16x8*)(ldsb + aoff + m*1024);
#pragma unroll
    for (int n = 0; n < 4; ++n) bg[n] = *(const bf16x8*)(ldsb + boff + n*1024);
#pragma unroll
    for (int m = 0; m < 4; ++m)
#pragma unroll
      for (int n = 0; n < 4; ++n)
        acc[m][n] = MFMA16(af[m], bg[n], acc[m][n]);
  }
}

// ---------------- proj GEMM: yb[4096][1024] @ wpT -> out fp32 + bias ----------------
__global__ __launch_bounds__(256,2) void k_gemm_proj(const unsigned short* __restrict__ yb,
    const unsigned short* __restrict__ wpT, const float* __restrict__ b_proj,
    float* __restrict__ out)
{
  __shared__ unsigned short lds[8192];
  f32x4 acc[4][4];
#pragma unroll
  for (int m = 0; m < 4; ++m)
#pragma unroll
    for (int n = 0; n < 4; ++n) acc[m][n] = (f32x4){0.f,0.f,0.f,0.f};
  int wgid = blockIdx.y * gridDim.x + blockIdx.x;
  const int cpx = (gridDim.x * gridDim.y) >> 3;
  wgid = (wgid & 7) * cpx + (wgid >> 3);
  const int bm = (wgid / gridDim.x) * 128, bn = (wgid % gridDim.x) * 128;
  gemm_core(yb, wpT, 1024, bm, bn, lds, acc);
  const int lane = threadIdx.x & 63, wave = threadIdx.x >> 6;
  const int wr = wave >> 1, wc = wave & 1, l15 = lane & 15, lg = lane >> 4;
#pragma unroll
  for (int m = 0; m < 4; ++m){
#pragma unroll
    for (int n = 0; n < 4; ++n){
#pragma unroll
      for (int r = 0; r < 4; ++r){
        const int row = bm + wr*64 + m*16 + lg*4 + r;
        const int col = bn + wc*64 + n*16 + l15;
        out[(size_t)row*1024 + col] = acc[m][n][r] + b_proj[col];
      }
    }
  }
}

// ---------------- flash attention: 4 waves/block share a 128-row q-block ----------------
__global__ __launch_bounds__(256,2) void k_attn(const unsigned short* __restrict__ q,
                       const unsigned short* __restrict__ kt,
                       const unsigned short* __restrict__ vt,
                       unsigned short* __restrict__ y)
{
  __shared__ char lds[32768];
  const int tid = threadIdx.x, lane = tid & 63, wave = tid >> 6;
  const int l31 = lane & 31, hi = lane >> 5;
  const int i = blockIdx.x, ii = i & 255;
  const int bh = ii & 31;
  const int qbi = (i < 256) ? (15 - (ii >> 5)) : (ii >> 5);
  const int q0w = qbi*128 + wave*32;
  const int ntiles = (qbi + 1) * 2;
  const unsigned short* qh = q + (size_t)bh * 131072;
  const char* kbase = (const char*)(kt + (size_t)bh * 131072);
  const char* vbase = (const char*)(vt + (size_t)bh * 131072);

  const float C = 0.125f * LOG2E;
  const float M = 16.0f;

  bf16x8 qf[4];
  {
    const unsigned short* qp = qh + (size_t)(q0w + l31)*64 + hi*8;
#pragma unroll
    for (int ds = 0; ds < 4; ++ds) qf[ds] = *(const bf16x8*)(qp + ds*16);
  }

  f32x16 yac0 = zero16(), yac1 = zero16();
  float lsum = 0.f;
  const int mask_from = q0w >> 6;
  const int stg = tid * 16;
  const int dst = wave * 1024;
  char* ldsK = lds;
  char* ldsV = lds + 16384;

#define STAGE(tile, buf) do { \
    const char* ks_ = kbase + (size_t)(tile)*8192; \
    const char* vs_ = vbase + (size_t)(tile)*8192; \
    gload_lds16(ks_ + stg,        ldsK + (buf)*8192 + dst); \
    gload_lds16(ks_ + 4096 + stg, ldsK + (buf)*8192 + 4096 + dst); \
    gload_lds16(vs_ + stg,        ldsV + (buf)*8192 + dst); \
    gload_lds16(vs_ + 4096 + stg, ldsV + (buf)*8192 + 4096 + dst); \
  } while(0)

  STAGE(0, 0);
  __syncthreads();

  const int swz = (l31 & 7) << 4;
  const int rowb = l31 * 128;

  for (int t = 0; t < ntiles; ++t){
    const int buf = t & 1;
    if (t + 1 < ntiles) STAGE(t + 1, buf ^ 1);

    const char* kb_ = ldsK + buf*8192;
    const char* vb_ = ldsV + buf*8192;

    bf16x8 kf[8];
#pragma unroll
    for (int ds = 0; ds < 4; ++ds){
      const int ch = ((ds*2 + hi) << 4) ^ swz;
      kf[ds]   = *(const bf16x8*)(kb_ + rowb + ch);
      kf[ds+4] = *(const bf16x8*)(kb_ + 4096 + rowb + ch);
    }
    f32x16 s0 = zero16(), s1 = zero16();
#pragma unroll
    for (int ds = 0; ds < 4; ++ds){
      s0 = MFMA32(kf[ds],   qf[ds], s0);
      s1 = MFMA32(kf[ds+4], qf[ds], s1);
    }

    bf16x8 vf[8];
#pragma unroll
    for (int ks = 0; ks < 4; ++ks){
      const int ch = ((ks*2 + hi) << 4) ^ swz;
      vf[ks]   = *(const bf16x8*)(vb_ + rowb + ch);
      vf[ks+4] = *(const bf16x8*)(vb_ + 4096 + rowb + ch);
    }

    if (t >= mask_from){
      const int qg = q0w + l31, key0 = t << 6;
#pragma unroll
      for (int r = 0; r < 16; ++r){
        const int kl = (r&3) + 8*(r>>2) + 4*hi;
        if (key0 + kl      > qg) s0[r] = -1e30f;
        if (key0 + 32 + kl > qg) s1[r] = -1e30f;
      }
    }

    float p0[16], p1[16];
    float ts = 0.f;
#pragma unroll
    for (int r = 0; r < 16; ++r){
      p0[r] = __builtin_amdgcn_exp2f(__builtin_fmaf(s0[r], C, -M));
      p1[r] = __builtin_amdgcn_exp2f(__builtin_fmaf(s1[r], C, -M));
      ts += p0[r] + p1[r];
    }
    lsum += ts;

    bf16x8 pa[4];
    pack_group(p0, pa[0], pa[1]);
    pack_group(p1, pa[2], pa[3]);
#pragma unroll
    for (int ks = 0; ks < 4; ++ks){
      yac0 = MFMA32(pa[ks], vf[ks],   yac0);
      yac1 = MFMA32(pa[ks], vf[ks+4], yac1);
    }
    __syncthreads();
  }
#undef STAGE

  lsum += __shfl_xor(lsum, 32);
  const float linv = 1.0f / lsum;
  const int b = bh >> 4, h = bh & 15;
  unsigned short* yp = y + ((size_t)b*2048 + q0w)*1024 + h*64;
#pragma unroll
  for (int r = 0; r < 16; ++r){
    const int ql = (r&3) + 8*(r>>2) + 4*hi;
    const float li = __shfl(linv, ql);
    yp[(size_t)ql*1024 + l31]      = f2bf(yac0[r] * li);
    yp[(size_t)ql*1024 + 32 + l31] = f2bf(yac1[r] * li);
  }
}

extern "C" void kernel_launch(void* const* d_in, const int* in_sizes, int n_in,
                              void* d_out, int out_size, void* d_ws, size_t ws_size,
                              hipStream_t stream) {
  const float* x      = (const float*)d_in[0];
  const float* w_attn = (const float*)d_in[1];
  const float* b_attn = (const float*)d_in[2];
  const float* w_proj = (const float*)d_in[3];
  const float* b_proj = (const float*)d_in[4];
  float* out = (float*)d_out;

  unsigned short* ws  = (unsigned short*)d_ws;
  unsigned short* xb  = ws;                    // 4096x1024
  unsigned short* waT = xb  + 4194304;         // 3072x1024
  unsigned short* wpT = waT + 3145728;         // 1024x1024
  unsigned short* qb  = wpT + 1048576;         // [B,H,T,D]
  unsigned short* kb  = qb  + 4194304;         // [B,H][tile][64key][64d] swz
  unsigned short* vb  = kb  + 4194304;         // [B,H][tile][64d][64key] swz
  unsigned short* yb  = vb  + 4194304;         // 4096x1024

  k_cast<<<dim3(4096), dim3(256), 0, stream>>>(x, xb);
  k_castT<<<dim3(48,16), dim3(256), 0, stream>>>(w_attn, waT, 1024, 3072);
  k_castT<<<dim3(16,16), dim3(256), 0, stream>>>(w_proj, wpT, 1024, 1024);
  k_gemm_qkv<<<dim3(12,16), dim3(512), 0, stream>>>(xb, waT, b_attn, qb, kb, vb);
  k_attn<<<dim3(512), dim3(256), 0, stream>>>(qb, kb, vb, yb);
  k_gemm_proj<<<dim3(8,32), dim3(256), 0, stream>>>(yb, wpT, b_proj, out);
}

// Round 7
// 100.960 us; speedup vs baseline: 1.0761x; 1.0761x over previous
//
#include <hip/hip_runtime.h>
#include <hip/hip_bf16.h>

typedef __attribute__((ext_vector_type(4))) float f32x4;
typedef __attribute__((ext_vector_type(16))) float f32x16;
typedef __attribute__((ext_vector_type(8))) short bf16x8;
typedef __attribute__((ext_vector_type(4))) unsigned int u32x4;

#define MFMA16(a,b,c) __builtin_amdgcn_mfma_f32_16x16x32_bf16(a,b,c,0,0,0)
#define MFMA32(a,b,c) __builtin_amdgcn_mfma_f32_32x32x16_bf16(a,b,c,0,0,0)
#define LOG2E 1.44269504088896340736f

__device__ __forceinline__ float bf2f(unsigned short u){
  unsigned v = ((unsigned)u) << 16;
  float f; __builtin_memcpy(&f, &v, 4); return f;
}
__device__ __forceinline__ unsigned short f2bf(float f){
  unsigned x; __builtin_memcpy(&x, &f, 4);
  x += 0x7fffu + ((x >> 16) & 1u);   // RNE
  return (unsigned short)(x >> 16);
}
__device__ __forceinline__ void gload_lds16(const void* g, void* l){
  __builtin_amdgcn_global_load_lds((const __attribute__((address_space(1))) void*)g,
                                   (__attribute__((address_space(3))) void*)l, 16, 0, 0);
}
__device__ __forceinline__ f32x16 zero16(){
  f32x16 z;
#pragma unroll
  for (int i = 0; i < 16; ++i) z[i] = 0.f;
  return z;
}
__device__ __forceinline__ unsigned cvtpk(float lo, float hi_){
  unsigned d;
  asm("v_cvt_pk_bf16_f32 %0, %1, %2" : "=v"(d) : "v"(lo), "v"(hi_));
  return d;
}
// pack 16 per-lane P values (key map (r&3)+8*(r>>2)+4*hi) into two PV A-frags
__device__ __forceinline__ void pack_group(const float* p, bf16x8& f0, bf16x8& f1){
  unsigned a0 = cvtpk(p[0], p[1]),  b0 = cvtpk(p[4],  p[5]);
  unsigned a1 = cvtpk(p[2], p[3]),  b1 = cvtpk(p[6],  p[7]);
  unsigned c0 = cvtpk(p[8], p[9]),  d0 = cvtpk(p[12], p[13]);
  unsigned c1 = cvtpk(p[10],p[11]), d1 = cvtpk(p[14], p[15]);
  asm("v_permlane32_swap_b32 %0, %1" : "+v"(a0), "+v"(b0));
  asm("v_permlane32_swap_b32 %0, %1" : "+v"(a1), "+v"(b1));
  asm("v_permlane32_swap_b32 %0, %1" : "+v"(c0), "+v"(d0));
  asm("v_permlane32_swap_b32 %0, %1" : "+v"(c1), "+v"(d1));
  u32x4 w0 = {a0, a1, b0, b1};
  u32x4 w1 = {c0, c1, d0, d1};
  f0 = __builtin_bit_cast(bf16x8, w0);
  f1 = __builtin_bit_cast(bf16x8, w1);
}

// ---------------- cast x (fp32 -> bf16), 4 elems/thread ----------------
__global__ void k_cast(const float* __restrict__ src, unsigned short* __restrict__ dst){
  const int i = blockIdx.x * 256 + threadIdx.x;
  const float4 v = ((const float4*)src)[i];
  ushort4 o;
  o.x = f2bf(v.x); o.y = f2bf(v.y); o.z = f2bf(v.z); o.w = f2bf(v.w);
  ((ushort4*)dst)[i] = o;
}

// ---------------- transpose-cast weights: src [R][C] f32 -> dst [C][R] bf16 ----------------
__global__ void k_castT(const float* __restrict__ src, unsigned short* __restrict__ dst,
                        const int R, const int C){
  __shared__ unsigned short t[64][65];
  const int r0 = blockIdx.y * 64, c0 = blockIdx.x * 64;
  const int tid = threadIdx.x;
#pragma unroll
  for (int i = 0; i < 16; ++i){
    int idx = i*256 + tid; int r = idx >> 6, c = idx & 63;
    t[r][c] = f2bf(src[(size_t)(r0 + r)*C + c0 + c]);
  }
  __syncthreads();
#pragma unroll
  for (int i = 0; i < 16; ++i){
    int idx = i*256 + tid; int c = idx >> 6, r = idx & 63;
    dst[(size_t)(c0 + c)*R + r0 + r] = t[r][c];
  }
}

// ======= GEMM mainloop v3: 128x128 tile, BK=32, TRIPLE-buffered LDS, 1 barrier/K-step =======
// Sync pattern (race-safe): each wave waits ITS OWN tile-t loads (vmcnt(4)) BEFORE the
// barrier; the barrier then certifies the whole tile for all waves (RAW), and also that
// everyone's iter t-1 ds_reads are done, so staging tile t+2 into buf[(t+2)%3] (last read
// at iter t-1) after the barrier is WAR-safe. Depth-2 prefetch: vmcnt never 0 mid-loop.
// LDS swizzle: 16B chunk ch' = ch ^ ((row>>1)&3), applied on BOTH sides
// (pre-swizzled global source + XOR'd read) -> conflict-free ds_read_b128.
__device__ __forceinline__ void gemm_core3(const unsigned short* __restrict__ A,
                                           const unsigned short* __restrict__ Bt,
                                           const int K, const int bm, const int bn,
                                           char* ldsb, f32x4 acc[4][4])
{
  const int tid = threadIdx.x, lane = tid & 63, wave = tid >> 6;
  const int wr = wave >> 1, wc = wave & 1;
  const int l15 = lane & 15, lg = lane >> 4;
  // staging: 4 x gload_lds16 per K-step (A 8KB + B 8KB), linear LDS dest
  const int o = tid * 16;                    // 0..4095 within each 4KB slab
  const int srow = o >> 6;                   // 0..63 (64B per row of 32 k-elems)
  const int sch = ((o >> 4) & 3) ^ ((srow >> 1) & 3);
  const unsigned short* gA0 = A  + (size_t)(bm + srow)*K      + sch*8;
  const unsigned short* gA1 = A  + (size_t)(bm + 64 + srow)*K + sch*8;
  const unsigned short* gB0 = Bt + (size_t)(bn + srow)*K      + sch*8;
  const unsigned short* gB1 = Bt + (size_t)(bn + 64 + srow)*K + sch*8;
  // fragment reads: row = (...)+l15, chunk lg read at lg ^ ((l15>>1)&3)
  const int rsw = (l15 >> 1) & 3;
  const int aoff = (wr*64 + l15)*64 + ((lg ^ rsw) << 4);
  const int boff = 8192 + (wc*64 + l15)*64 + ((lg ^ rsw) << 4);

#define STG3(koff, bb) do { \
    gload_lds16(gA0 + (koff), ldsb + (bb) + o); \
    gload_lds16(gA1 + (koff), ldsb + (bb) + 4096 + o); \
    gload_lds16(gB0 + (koff), ldsb + (bb) + 8192 + o); \
    gload_lds16(gB1 + (koff), ldsb + (bb) + 12288 + o); } while(0)

  const int NT = K >> 5;
  STG3(0, 0);                                // tile 0 -> buf 0
  STG3(32, 16384);                           // tile 1 -> buf 1
  int bcur = 0, bstg = 32768;                // compute buf (t%3), stage buf ((t+2)%3)
  for (int t = 0; t < NT; ++t){
    if (t + 1 < NT) asm volatile("s_waitcnt vmcnt(4)" ::: "memory");  // own tile-t landed
    else            asm volatile("s_waitcnt vmcnt(0)" ::: "memory");
    __builtin_amdgcn_s_barrier();            // tile t visible to all; iter t-1 reads done
    __builtin_amdgcn_sched_barrier(0);
    if (t + 2 < NT) STG3((size_t)(t + 2) << 5, bstg);
    bf16x8 af[4], bg[4];
#pragma unroll
    for (int m = 0; m < 4; ++m) af[m] = *(const bf16x8*)(ldsb + bcur + aoff + m*1024);
#pragma unroll
    for (int n = 0; n < 4; ++n) bg[n] = *(const bf16x8*)(ldsb + bcur + boff + n*1024);
    __builtin_amdgcn_s_setprio(1);
#pragma unroll
    for (int m = 0; m < 4; ++m)
#pragma unroll
      for (int n = 0; n < 4; ++n)
        acc[m][n] = MFMA16(af[m], bg[n], acc[m][n]);
    __builtin_amdgcn_s_setprio(0);
    bcur = (bcur == 32768) ? 0 : bcur + 16384;
    bstg = (bstg == 32768) ? 0 : bstg + 16384;
  }
#undef STG3
}

// ---------------- QKV GEMM: xb[4096][1024] @ waT -> q [B,H,T,D]; k,v tiled-swizzled ----------------
__global__ __launch_bounds__(256,3) void k_gemm_qkv(const unsigned short* __restrict__ xb,
    const unsigned short* __restrict__ waT, const float* __restrict__ b_attn,
    unsigned short* __restrict__ qb, unsigned short* __restrict__ kb,
    unsigned short* __restrict__ vb)
{
  __shared__ char lds[49152];
  f32x4 acc[4][4];
#pragma unroll
  for (int m = 0; m < 4; ++m)
#pragma unroll
    for (int n = 0; n < 4; ++n) acc[m][n] = (f32x4){0.f,0.f,0.f,0.f};
  // bijective XCD swizzle (nwg = 768, %8==0)
  int wgid = blockIdx.y * 24 + blockIdx.x;
  wgid = (wgid & 7) * 96 + (wgid >> 3);
  const int bm = (wgid / 24) * 128, bn = (wgid % 24) * 128;
  gemm_core3(xb, waT, 1024, bm, bn, lds, acc);
  const int lane = threadIdx.x & 63, wave = threadIdx.x >> 6;
  const int wr = wave >> 1, wc = wave & 1, l15 = lane & 15, lg = lane >> 4;
#pragma unroll
  for (int m = 0; m < 4; ++m){
#pragma unroll
    for (int n = 0; n < 4; ++n){
#pragma unroll
      for (int r = 0; r < 4; ++r){
        const int row = bm + wr*64 + m*16 + lg*4 + r;
        const int col = bn + wc*64 + n*16 + l15;
        const float val = acc[m][n][r] + b_attn[col];
        const int part = col >> 10, c = col & 1023;
        const int h = c >> 6, d = c & 63;
        const int b = row >> 11, t = row & 2047;
        const unsigned short u = f2bf(val);
        const size_t bhbase = (size_t)(b*16 + h)*131072;
        if (part == 0){
          qb[bhbase + (size_t)t*64 + d] = u;
        } else {
          const int tile = t >> 6, l = t & 63;
          const size_t base = bhbase + (size_t)tile*4096;
          if (part == 1) kb[base + l*64 + ((((d>>3)^(l&7))<<3) | (d&7))] = u;   // K[key][d], swz
          else           vb[base + d*64 + ((((l>>3)^(d&7))<<3) | (l&7))] = u;   // V^T[d][key], swz
        }
      }
    }
  }
}

// ---------------- proj GEMM: yb[4096][1024] @ wpT -> out fp32 + bias ----------------
__global__ __launch_bounds__(256,3) void k_gemm_proj(const unsigned short* __restrict__ yb,
    const unsigned short* __restrict__ wpT, const float* __restrict__ b_proj,
    float* __restrict__ out)
{
  __shared__ char lds[49152];
  f32x4 acc[4][4];
#pragma unroll
  for (int m = 0; m < 4; ++m)
#pragma unroll
    for (int n = 0; n < 4; ++n) acc[m][n] = (f32x4){0.f,0.f,0.f,0.f};
  // bijective XCD swizzle (nwg = 256, %8==0)
  int wgid = blockIdx.y * 8 + blockIdx.x;
  wgid = (wgid & 7) * 32 + (wgid >> 3);
  const int bm = (wgid / 8) * 128, bn = (wgid % 8) * 128;
  gemm_core3(yb, wpT, 1024, bm, bn, lds, acc);
  const int lane = threadIdx.x & 63, wave = threadIdx.x >> 6;
  const int wr = wave >> 1, wc = wave & 1, l15 = lane & 15, lg = lane >> 4;
#pragma unroll
  for (int m = 0; m < 4; ++m){
#pragma unroll
    for (int n = 0; n < 4; ++n){
#pragma unroll
      for (int r = 0; r < 4; ++r){
        const int row = bm + wr*64 + m*16 + lg*4 + r;
        const int col = bn + wc*64 + n*16 + l15;
        out[(size_t)row*1024 + col] = acc[m][n][r] + b_proj[col];
      }
    }
  }
}

// ---------------- flash attention: 4 waves/block share a 128-row q-block ----------------
__global__ __launch_bounds__(256,2) void k_attn(const unsigned short* __restrict__ q,
                       const unsigned short* __restrict__ kt,
                       const unsigned short* __restrict__ vt,
                       unsigned short* __restrict__ y)
{
  __shared__ char lds[32768];
  const int tid = threadIdx.x, lane = tid & 63, wave = tid >> 6;
  const int l31 = lane & 31, hi = lane >> 5;
  const int i = blockIdx.x, ii = i & 255;
  const int bh = ii & 31;
  const int qbi = (i < 256) ? (15 - (ii >> 5)) : (ii >> 5);
  const int q0w = qbi*128 + wave*32;
  const int ntiles = (qbi + 1) * 2;
  const unsigned short* qh = q + (size_t)bh * 131072;
  const char* kbase = (const char*)(kt + (size_t)bh * 131072);
  const char* vbase = (const char*)(vt + (size_t)bh * 131072);

  const float C = 0.125f * LOG2E;
  const float M = 16.0f;

  bf16x8 qf[4];
  {
    const unsigned short* qp = qh + (size_t)(q0w + l31)*64 + hi*8;
#pragma unroll
    for (int ds = 0; ds < 4; ++ds) qf[ds] = *(const bf16x8*)(qp + ds*16);
  }

  f32x16 yac0 = zero16(), yac1 = zero16();
  float lsum = 0.f;
  const int mask_from = q0w >> 6;
  const int stg = tid * 16;
  const int dst = wave * 1024;
  char* ldsK = lds;
  char* ldsV = lds + 16384;

#define STAGE(tile, buf) do { \
    const char* ks_ = kbase + (size_t)(tile)*8192; \
    const char* vs_ = vbase + (size_t)(tile)*8192; \
    gload_lds16(ks_ + stg,        ldsK + (buf)*8192 + dst); \
    gload_lds16(ks_ + 4096 + stg, ldsK + (buf)*8192 + 4096 + dst); \
    gload_lds16(vs_ + stg,        ldsV + (buf)*8192 + dst); \
    gload_lds16(vs_ + 4096 + stg, ldsV + (buf)*8192 + 4096 + dst); \
  } while(0)

  STAGE(0, 0);
  __syncthreads();

  const int swz = (l31 & 7) << 4;
  const int rowb = l31 * 128;

  for (int t = 0; t < ntiles; ++t){
    const int buf = t & 1;
    if (t + 1 < ntiles) STAGE(t + 1, buf ^ 1);

    const char* kb_ = ldsK + buf*8192;
    const char* vb_ = ldsV + buf*8192;

    bf16x8 kf[8];
#pragma unroll
    for (int ds = 0; ds < 4; ++ds){
      const int ch = ((ds*2 + hi) << 4) ^ swz;
      kf[ds]   = *(const bf16x8*)(kb_ + rowb + ch);
      kf[ds+4] = *(const bf16x8*)(kb_ + 4096 + rowb + ch);
    }
    f32x16 s0 = zero16(), s1 = zero16();
#pragma unroll
    for (int ds = 0; ds < 4; ++ds){
      s0 = MFMA32(kf[ds],   qf[ds], s0);
      s1 = MFMA32(kf[ds+4], qf[ds], s1);
    }

    bf16x8 vf[8];
#pragma unroll
    for (int ks = 0; ks < 4; ++ks){
      const int ch = ((ks*2 + hi) << 4) ^ swz;
      vf[ks]   = *(const bf16x8*)(vb_ + rowb + ch);
      vf[ks+4] = *(const bf16x8*)(vb_ + 4096 + rowb + ch);
    }

    if (t >= mask_from){
      const int qg = q0w + l31, key0 = t << 6;
#pragma unroll
      for (int r = 0; r < 16; ++r){
        const int kl = (r&3) + 8*(r>>2) + 4*hi;
        if (key0 + kl      > qg) s0[r] = -1e30f;
        if (key0 + 32 + kl > qg) s1[r] = -1e30f;
      }
    }

    float p0[16], p1[16];
    float ts = 0.f;
#pragma unroll
    for (int r = 0; r < 16; ++r){
      p0[r] = __builtin_amdgcn_exp2f(__builtin_fmaf(s0[r], C, -M));
      p1[r] = __builtin_amdgcn_exp2f(__builtin_fmaf(s1[r], C, -M));
      ts += p0[r] + p1[r];
    }
    lsum += ts;

    bf16x8 pa[4];
    pack_group(p0, pa[0], pa[1]);
    pack_group(p1, pa[2], pa[3]);
#pragma unroll
    for (int ks = 0; ks < 4; ++ks){
      yac0 = MFMA32(pa[ks], vf[ks],   yac0);
      yac1 = MFMA32(pa[ks], vf[ks+4], yac1);
    }
    __syncthreads();
  }
#undef STAGE

  lsum += __shfl_xor(lsum, 32);
  const float linv = 1.0f / lsum;
  const int b = bh >> 4, h = bh & 15;
  unsigned short* yp = y + ((size_t)b*2048 + q0w)*1024 + h*64;
#pragma unroll
  for (int r = 0; r < 16; ++r){
    const int ql = (r&3) + 8*(r>>2) + 4*hi;
    const float li = __shfl(linv, ql);
    yp[(size_t)ql*1024 + l31]      = f2bf(yac0[r] * li);
    yp[(size_t)ql*1024 + 32 + l31] = f2bf(yac1[r] * li);
  }
}

extern "C" void kernel_launch(void* const* d_in, const int* in_sizes, int n_in,
                              void* d_out, int out_size, void* d_ws, size_t ws_size,
                              hipStream_t stream) {
  const float* x      = (const float*)d_in[0];
  const float* w_attn = (const float*)d_in[1];
  const float* b_attn = (const float*)d_in[2];
  const float* w_proj = (const float*)d_in[3];
  const float* b_proj = (const float*)d_in[4];
  float* out = (float*)d_out;

  unsigned short* ws  = (unsigned short*)d_ws;
  unsigned short* xb  = ws;                    // 4096x1024
  unsigned short* waT = xb  + 4194304;         // 3072x1024
  unsigned short* wpT = waT + 3145728;         // 1024x1024
  unsigned short* qb  = wpT + 1048576;         // [B,H,T,D]
  unsigned short* kb  = qb  + 4194304;         // [B,H][tile][64key][64d] swz
  unsigned short* vb  = kb  + 4194304;         // [B,H][tile][64d][64key] swz
  unsigned short* yb  = vb  + 4194304;         // 4096x1024

  k_cast<<<dim3(4096), dim3(256), 0, stream>>>(x, xb);
  k_castT<<<dim3(48,16), dim3(256), 0, stream>>>(w_attn, waT, 1024, 3072);
  k_castT<<<dim3(16,16), dim3(256), 0, stream>>>(w_proj, wpT, 1024, 1024);
  k_gemm_qkv<<<dim3(24,32), dim3(256), 0, stream>>>(xb, waT, b_attn, qb, kb, vb);
  k_attn<<<dim3(512), dim3(256), 0, stream>>>(qb, kb, vb, yb);
  k_gemm_proj<<<dim3(8,32), dim3(256), 0, stream>>>(yb, wpT, b_proj, out);
}